// Round 3
// baseline (277.449 us; speedup 1.0000x reference)
//
#include <hip/hip_runtime.h>

// Problem constants (fixed by setup_inputs: 4096x4096 fp32).
#define H 4096
#define W 4096
#define TILE 64
#define PADR 7                    // max k = 15 -> radius 7
#define PT (TILE + 2 * PADR)      // 78 padded tile extent
#define PROWS (PT + 1)            // 79 (row/col 0 are prefix zeros)
#define STRIDE 81                 // odd stride: scan lanes spread over all 32 banks

// Diagonal-segment decomposition:
//   out(i,j) = sum_d h[d]*Ppre(i+d, j+d)  -  sum_d h[d]*Ppre(i+d, j+15-d)
// with h[d] = h[15-d], h[7]=h[8]=0, h[d] = 1/(7*(15-2d)^2) for d in 0..6.
// Each thread walks a 32-pixel diagonal (pass 1: main diag, +acc into LDS;
// pass 2: anti diag, finalize * base -> out). 47 P reads serve 32 pixels.

__global__ __launch_bounds__(256) void multi_box_kernel(
    const float* __restrict__ x,
    const float* __restrict__ base,
    float* __restrict__ out)
{
    // +32 front bias so the smallest (masked-pixel-only) read index stays >= 0;
    // +128 tail pad so the largest (masked-only) read stays inside our alloc.
    __shared__ float Pbuf[32 + PROWS * STRIDE + 128];   // ~26.2 KB
    __shared__ float Acc[TILE * TILE];                  // 16 KB
    float* P = Pbuf + 32;

    const int tid = threadIdx.x;
    const int bx0 = blockIdx.x * TILE;
    const int by0 = blockIdx.y * TILE;

    // ---- Stage A: load padded tile into P[1..78][1..78]; clamp = replicate pad ----
    for (int idx = tid; idx < PT * PT; idx += 256) {
        int i = idx / PT;
        int j = idx - i * PT;
        int gy = min(max(by0 + i - PADR, 0), H - 1);
        int gx = min(max(bx0 + j - PADR, 0), W - 1);
        P[(i + 1) * STRIDE + (j + 1)] = x[gy * W + gx];
    }
    if (tid < PROWS) {
        P[tid] = 0.0f;            // prefix row 0
        P[tid * STRIDE] = 0.0f;   // prefix col 0
    }
    __syncthreads();

    // ---- Row prefix: thread t scans row t+1 (read2/write2-merged via full unroll) ----
    if (tid < PT) {
        float v = 0.0f;
        const int rb = (tid + 1) * STRIDE + 1;
        #pragma unroll
        for (int j = 0; j < PT; ++j) {
            v += P[rb + j];
            P[rb + j] = v;
        }
    }
    __syncthreads();

    // ---- Column prefix: thread t scans column t+1, groups of 4 rows ----
    if (tid < PT) {
        float v = 0.0f;
        int cb = STRIDE + (tid + 1);
        #pragma unroll 1
        for (int g = 0; g < PT / 4; ++g) {   // 19 groups of 4
            float a0 = P[cb];
            float a1 = P[cb + STRIDE];
            float a2 = P[cb + 2 * STRIDE];
            float a3 = P[cb + 3 * STRIDE];
            float v0 = v + a0;
            float v1 = v0 + a1;
            float v2 = v1 + a2;
            float v3 = v2 + a3;
            P[cb] = v0;
            P[cb + STRIDE] = v1;
            P[cb + 2 * STRIDE] = v2;
            P[cb + 3 * STRIDE] = v3;
            v = v3;
            cb += 4 * STRIDE;
        }
        float t0 = v + P[cb];            P[cb] = t0;
        float t1 = t0 + P[cb + STRIDE]; P[cb + STRIDE] = t1;
    }
    __syncthreads();
    // Now P[a*81 + b] = Ppre(a,b) = sum_{i<a, j<b} xp(i,j), a,b in [0,78].

    const int seg = tid;
    const bool active = seg < 190;                 // 2 x 95 segments, 3 waves
    const int i0 = (seg < 95) ? 0 : 32;
    const int jj = (seg < 95) ? seg : seg - 95;    // 0..94

    float vv[47];

    // ---- Pass 1: main diagonals. Pixel t at (i0+t, j0+t), j0 = jj-31. ----
    if (active) {
        const int j0 = jj - 31;                    // -31..63
        const int b = i0 * STRIDE + j0;            // index of v(0); >= -31 (bias covers)
        #pragma unroll
        for (int s = 0; s < 47; ++s)
            vv[s] = P[b + s * (STRIDE + 1)];       // v(s) = Ppre(i0+s, j0+s)
        #pragma unroll
        for (int t = 0; t < 32; ++t) {
            float a = 0.0f;
            #pragma unroll
            for (int d = 0; d < 7; ++d) {
                const float w = 1.0f / (7.0f * (float)((15 - 2 * d) * (15 - 2 * d)));
                a = fmaf(w, vv[t + d] + vv[t + 15 - d], a);
            }
            const int j = j0 + t;
            if ((unsigned)j < (unsigned)TILE)
                Acc[(i0 + t) * TILE + j] = a;
        }
    }
    __syncthreads();

    // ---- Pass 2: anti diagonals. Pixel t at (i0+t, j0a-t), j0a = jj. ----
    if (active) {
        const int j0a = jj;                        // 0..94
        const int b = i0 * STRIDE + (j0a + 15);    // index of u(0) = Ppre(i0, j0a+15)
        #pragma unroll
        for (int s = 0; s < 47; ++s)
            vv[s] = P[b + s * (STRIDE - 1)];       // u(s) = Ppre(i0+s, j0a+15-s)
        #pragma unroll
        for (int t = 0; t < 32; ++t) {
            float a = 0.0f;
            #pragma unroll
            for (int d = 0; d < 7; ++d) {
                const float w = 1.0f / (7.0f * (float)((15 - 2 * d) * (15 - 2 * d)));
                a = fmaf(w, vv[t + d] + vv[t + 15 - d], a);
            }
            const int j = j0a - t;
            if ((unsigned)j < (unsigned)TILE) {
                const int g = (by0 + i0 + t) * W + (bx0 + j);
                out[g] = (Acc[(i0 + t) * TILE + j] - a) * base[g];
            }
        }
    }
}

extern "C" void kernel_launch(void* const* d_in, const int* in_sizes, int n_in,
                              void* d_out, int out_size, void* d_ws, size_t ws_size,
                              hipStream_t stream) {
    const float* x    = (const float*)d_in[0];
    const float* base = (const float*)d_in[1];
    float* out        = (float*)d_out;

    dim3 grid(W / TILE, H / TILE);  // 64 x 64 tiles
    multi_box_kernel<<<grid, 256, 0, stream>>>(x, base, out);
}

// Round 4
// 239.018 us; speedup vs baseline: 1.1608x; 1.1608x over previous
//
#include <hip/hip_runtime.h>

// Problem constants (fixed by setup_inputs: 4096x4096 fp32).
#define H 4096
#define W 4096
#define TILE 64
#define PADR 7                    // max k = 15 -> radius 7
#define PT (TILE + 2 * PADR)      // 78 padded tile extent
#define PROWS (PT + 1)            // 79 (row/col 0 are prefix zeros)
#define STRIDE 81                 // odd stride: scan lanes spread over all 32 banks

// Diagonal-segment decomposition:
//   out(i,j) = sum_d h[d]*Ppre(i+d, j+d)  -  sum_d h[d]*Ppre(i+d, j+15-d)
// with h[d] = h[15-d], h[7]=h[8]=0, h[d] = 1/(7*(15-2d)^2) for d in 0..6.
// Pass 1 walks main diagonals and writes the weighted partial to out (global,
// coalesced per step; the block's own 16 KB region -> L2-resident).
// Pass 2 walks anti diagonals, finalizes (partial - a) * base -> out.
// LDS holds ONLY the 2D prefix P (26.3 KB) -> 6 blocks/CU.

__global__ __launch_bounds__(256) void multi_box_kernel(
    const float* __restrict__ x,
    const float* __restrict__ base,
    float* __restrict__ out)
{
    // +32 front bias so the smallest (masked-pixel-only) read index stays >= 0;
    // +128 tail pad so the largest (masked-only) read stays inside our alloc.
    __shared__ float Pbuf[32 + PROWS * STRIDE + 128];   // ~26.3 KB total
    float* P = Pbuf + 32;

    const int tid = threadIdx.x;
    const int bx0 = blockIdx.x * TILE;
    const int by0 = blockIdx.y * TILE;

    // ---- Stage A: load padded tile into P[1..78][1..78]; clamp = replicate pad ----
    for (int idx = tid; idx < PT * PT; idx += 256) {
        int i = idx / PT;
        int j = idx - i * PT;
        int gy = min(max(by0 + i - PADR, 0), H - 1);
        int gx = min(max(bx0 + j - PADR, 0), W - 1);
        P[(i + 1) * STRIDE + (j + 1)] = x[gy * W + gx];
    }
    if (tid < PROWS) {
        P[tid] = 0.0f;            // prefix row 0
        P[tid * STRIDE] = 0.0f;   // prefix col 0
    }
    __syncthreads();

    // ---- Row prefix: thread t scans row t+1 (read2/write2-merged via full unroll) ----
    if (tid < PT) {
        float v = 0.0f;
        const int rb = (tid + 1) * STRIDE + 1;
        #pragma unroll
        for (int j = 0; j < PT; ++j) {
            v += P[rb + j];
            P[rb + j] = v;
        }
    }
    __syncthreads();

    // ---- Column prefix: thread t scans column t+1, groups of 4 rows ----
    if (tid < PT) {
        float v = 0.0f;
        int cb = STRIDE + (tid + 1);
        #pragma unroll 1
        for (int g = 0; g < PT / 4; ++g) {   // 19 groups of 4
            float a0 = P[cb];
            float a1 = P[cb + STRIDE];
            float a2 = P[cb + 2 * STRIDE];
            float a3 = P[cb + 3 * STRIDE];
            float v0 = v + a0;
            float v1 = v0 + a1;
            float v2 = v1 + a2;
            float v3 = v2 + a3;
            P[cb] = v0;
            P[cb + STRIDE] = v1;
            P[cb + 2 * STRIDE] = v2;
            P[cb + 3 * STRIDE] = v3;
            v = v3;
            cb += 4 * STRIDE;
        }
        float t0 = v + P[cb];            P[cb] = t0;
        float t1 = t0 + P[cb + STRIDE]; P[cb + STRIDE] = t1;
    }
    __syncthreads();
    // Now P[a*81 + b] = Ppre(a,b), a,b in [0,78].

    const int seg = tid;
    const bool active = seg < 190;                 // 2 x 95 segments, 3 waves
    const int i0 = (seg < 95) ? 0 : 32;
    const int jj = (seg < 95) ? seg : seg - 95;    // 0..94

    float vv[47];

    // ---- Pass 1: main diagonals. Pixel t at (i0+t, j0+t), j0 = jj-31.
    //      Writes weighted partial to out (coalesced; every tile pixel hit once).
    if (active) {
        const int j0 = jj - 31;                    // -31..63
        const int b = i0 * STRIDE + j0;            // >= -31 (front bias covers)
        #pragma unroll
        for (int s = 0; s < 47; ++s)
            vv[s] = P[b + s * (STRIDE + 1)];       // v(s) = Ppre(i0+s, j0+s)
        #pragma unroll
        for (int t = 0; t < 32; ++t) {
            const int j = j0 + t;
            if ((unsigned)j < (unsigned)TILE) {
                float a = 0.0f;
                #pragma unroll
                for (int d = 0; d < 7; ++d) {
                    const float w = 1.0f / (7.0f * (float)((15 - 2 * d) * (15 - 2 * d)));
                    a = fmaf(w, vv[t + d] + vv[t + 15 - d], a);
                }
                out[(by0 + i0 + t) * W + (bx0 + j)] = a;
            }
        }
    }
    __syncthreads();   // drains vmcnt(0) before barrier; same-CU L1/L2 serve re-reads

    // ---- Pass 2: anti diagonals. Pixel t at (i0+t, j0a-t), j0a = jj. ----
    if (active) {
        const int j0a = jj;                        // 0..94
        const int b = i0 * STRIDE + (j0a + 15);    // u(0) = Ppre(i0, j0a+15)
        #pragma unroll
        for (int s = 0; s < 47; ++s)
            vv[s] = P[b + s * (STRIDE - 1)];       // u(s) = Ppre(i0+s, j0a+15-s)
        #pragma unroll
        for (int t = 0; t < 32; ++t) {
            const int j = j0a - t;
            if ((unsigned)j < (unsigned)TILE) {
                float a = 0.0f;
                #pragma unroll
                for (int d = 0; d < 7; ++d) {
                    const float w = 1.0f / (7.0f * (float)((15 - 2 * d) * (15 - 2 * d)));
                    a = fmaf(w, vv[t + d] + vv[t + 15 - d], a);
                }
                const int g = (by0 + i0 + t) * W + (bx0 + j);
                out[g] = (out[g] - a) * base[g];
            }
        }
    }
}

extern "C" void kernel_launch(void* const* d_in, const int* in_sizes, int n_in,
                              void* d_out, int out_size, void* d_ws, size_t ws_size,
                              hipStream_t stream) {
    const float* x    = (const float*)d_in[0];
    const float* base = (const float*)d_in[1];
    float* out        = (float*)d_out;

    dim3 grid(W / TILE, H / TILE);  // 64 x 64 tiles
    multi_box_kernel<<<grid, 256, 0, stream>>>(x, base, out);
}